// Round 1
// baseline (285.202 us; speedup 1.0000x reference)
//
#include <hip/hip_runtime.h>
#include <hip/hip_bf16.h>

// ---------------------------------------------------------------------------
// MultiHeadAttention: feats L2-norm + clamp(coords) concat -> per-head QKV
// (DIN=259, HD=32, H=8) -> softmax attention (N=4096, clip +-100, /(sum+1e-6))
// -> output proj + bias + residual.
// Precision: hi/lo bf16 split (3-MFMA fp32 emulation) for QKV proj and QK^T;
// V split + bf16 P for PV; plain bf16 for output proj.
// ---------------------------------------------------------------------------

using s8 = __attribute__((ext_vector_type(8))) short;   // 8 x bf16 (4 VGPR)
using f4 = __attribute__((ext_vector_type(4))) float;   // MFMA C/D
typedef unsigned short u16;
typedef unsigned int   u32;

#define NPTS 4096
#define NH   8
#define HD   32
#define DIN  259
#define DINP 288       // padded K-dim for QKV GEMM (9 x 32)
#define COUT 768       // 3*NH*HD, col c = s*256 + h*32 + hd (s: 0=q,1=k,2=v)

#define MFMA(a, b, c) __builtin_amdgcn_mfma_f32_16x16x32_bf16((a), (b), (c), 0, 0, 0)

__device__ __forceinline__ u16 f2bf(float f) {
    u32 u = __float_as_uint(f);
    u32 r = u + 0x7FFFu + ((u >> 16) & 1u);   // round-to-nearest-even
    return (u16)(r >> 16);
}
__device__ __forceinline__ float bf2f(u16 h) { return __uint_as_float(((u32)h) << 16); }
__device__ __forceinline__ void splitbf(float v, u16& hi, u16& lo) {
    hi = f2bf(v);
    lo = f2bf(v - bf2f(hi));
}
__device__ __forceinline__ s8 ld8(const u16* p) { return *reinterpret_cast<const s8*>(p); }

// ---------------------------------------------------------------------------
// Phase 0a: build transposed+split QKV weight matrix Wt[COUT][DINP]
// Wt[c][k] = w_s[h][k][hd] for k<DIN else 0, c = s*256 + h*32 + hd
// ---------------------------------------------------------------------------
__global__ void k_wprep(const float* __restrict__ wq, const float* __restrict__ wk,
                        const float* __restrict__ wv,
                        u16* __restrict__ wtHi, u16* __restrict__ wtLo) {
    int c = blockIdx.x;                   // 0..767
    int s = c >> 8, h = (c >> 5) & 7, hd = c & 31;
    const float* w = (s == 0) ? wq : (s == 1) ? wk : wv;
    for (int k = threadIdx.x; k < DINP; k += blockDim.x) {
        float val = (k < DIN) ? w[(h * DIN + k) * HD + hd] : 0.0f;
        u16 hi, lo; splitbf(val, hi, lo);
        wtHi[c * DINP + k] = hi;
        wtLo[c * DINP + k] = lo;
    }
}

// ---------------------------------------------------------------------------
// Phase 0b: woT[c][k] = wo[k][c] (bf16, single precision is enough here)
// ---------------------------------------------------------------------------
__global__ void k_woprep(const float* __restrict__ wo, u16* __restrict__ woT) {
    int c = blockIdx.x;
    int k = threadIdx.x;                  // blockDim = 256
    woT[c * 256 + k] = f2bf(wo[k * 256 + c]);
}

// ---------------------------------------------------------------------------
// Phase 1: xc[n][0..255] = x / (||x||+1e-6); xc[n][256..258] = clamp(coords);
// pad to DINP with zeros. Output hi/lo split bf16.  One 64-lane wave per row.
// ---------------------------------------------------------------------------
__global__ __launch_bounds__(64) void k_featurize(const float* __restrict__ x,
                                                  const int* __restrict__ coords,
                                                  u16* __restrict__ xcHi,
                                                  u16* __restrict__ xcLo) {
    int row = blockIdx.x;
    int l = threadIdx.x;
    f4 v = *reinterpret_cast<const f4*>(x + row * 256 + 4 * l);
    float ss = v[0] * v[0] + v[1] * v[1] + v[2] * v[2] + v[3] * v[3];
#pragma unroll
    for (int m = 1; m < 64; m <<= 1) ss += __shfl_xor(ss, m);
    float inv = 1.0f / (sqrtf(ss) + 1e-6f);
#pragma unroll
    for (int j = 0; j < 4; ++j) {
        u16 hi, lo; splitbf(v[j] * inv, hi, lo);
        xcHi[row * DINP + 4 * l + j] = hi;
        xcLo[row * DINP + 4 * l + j] = lo;
    }
    if (l < 32) {
        int col = 256 + l;
        float val = 0.0f;
        if (col < DIN) {
            float c = (float)coords[row * 3 + (col - 256)];
            val = fminf(fmaxf(c, -100.0f), 100.0f);
        }
        u16 hi, lo; splitbf(val, hi, lo);
        xcHi[row * DINP + col] = hi;
        xcLo[row * DINP + col] = lo;
    }
}

// ---------------------------------------------------------------------------
// Phase 2: QKV GEMM  [4096 x DINP] x [DINP x 768] with 3-MFMA emulation.
// Writes q,k row-major [h][n][hd] (hi/lo) and v transposed [h][hd][n] (hi/lo).
// Block: 256 thr = 4 waves; wave = 16 rows x 64 cols. Grid (64, 12).
// ---------------------------------------------------------------------------
__global__ __launch_bounds__(256) void k_qkv(
        const u16* __restrict__ xcHi, const u16* __restrict__ xcLo,
        const u16* __restrict__ wtHi, const u16* __restrict__ wtLo,
        const float* __restrict__ bq, const float* __restrict__ bk,
        const float* __restrict__ bv,
        u16* __restrict__ qHi, u16* __restrict__ qLo,
        u16* __restrict__ kHi, u16* __restrict__ kLo,
        u16* __restrict__ vtHi, u16* __restrict__ vtLo) {
    int w = threadIdx.x >> 6, l = threadIdx.x & 63;
    int lr = l & 15, lg = l >> 4;
    int r0 = blockIdx.x * 64 + w * 16;    // wave's row base
    int c0 = blockIdx.y * 64;             // block's col base

    f4 acc[4] = {};
    const u16* aH = xcHi + (r0 + lr) * DINP + lg * 8;
    const u16* aL = xcLo + (r0 + lr) * DINP + lg * 8;
#pragma unroll
    for (int kk = 0; kk < 9; ++kk) {
        s8 ah = ld8(aH + kk * 32);
        s8 al = ld8(aL + kk * 32);
#pragma unroll
        for (int ct = 0; ct < 4; ++ct) {
            int c = c0 + ct * 16 + lr;
            const u16* bp = wtHi + c * DINP + kk * 32 + lg * 8;
            const u16* bq_ = wtLo + c * DINP + kk * 32 + lg * 8;
            s8 bh = ld8(bp);
            s8 bl = ld8(bq_);
            acc[ct] = MFMA(al, bh, acc[ct]);
            acc[ct] = MFMA(ah, bl, acc[ct]);
            acc[ct] = MFMA(ah, bh, acc[ct]);
        }
    }
#pragma unroll
    for (int ct = 0; ct < 4; ++ct) {
        int c = c0 + ct * 16 + lr;
        int s = c >> 8, h = (c >> 5) & 7, hd = c & 31;
        float bias = ((s == 0) ? bq : (s == 1) ? bk : bv)[h * HD + hd];
#pragma unroll
        for (int r = 0; r < 4; ++r) {
            int n = r0 + lg * 4 + r;
            float val = acc[ct][r] + bias;
            u16 hi, lo; splitbf(val, hi, lo);
            if (s == 0) {
                qHi[(h * NPTS + n) * HD + hd] = hi;
                qLo[(h * NPTS + n) * HD + hd] = lo;
            } else if (s == 1) {
                kHi[(h * NPTS + n) * HD + hd] = hi;
                kLo[(h * NPTS + n) * HD + hd] = lo;
            } else {
                vtHi[(h * HD + hd) * NPTS + n] = hi;
                vtLo[(h * HD + hd) * NPTS + n] = lo;
            }
        }
    }
}

// ---------------------------------------------------------------------------
// Phase 3: attention. One 64-lane wave per (head, 16 q-rows). Online softmax.
// S tile = Q[16x32] . K^T -> 16x64 per iter via 3-MFMA emulation; clip; exp;
// P staged bf16 in LDS (D-layout -> A-layout); O += P.Vhi + P.Vlo.
// ---------------------------------------------------------------------------
__global__ __launch_bounds__(64) void k_attn(
        const u16* __restrict__ qHi, const u16* __restrict__ qLo,
        const u16* __restrict__ kHi, const u16* __restrict__ kLo,
        const u16* __restrict__ vtHi, const u16* __restrict__ vtLo,
        u16* __restrict__ catH) {
    __shared__ u16 pl[16 * 72];           // P tile [16 q][64 k] + pad 8
    int qb = blockIdx.x;                  // 0..255
    int h = blockIdx.y;                   // 0..7
    int l = threadIdx.x, lr = l & 15, lg = l >> 4;
    const float SCALE = 0.17677669529663687f;   // 1/sqrt(32)

    size_t qoff = (size_t)(h * NPTS + qb * 16 + lr) * HD + lg * 8;
    s8 qh = ld8(qHi + qoff);
    s8 ql = ld8(qLo + qoff);

    float m[4], sum[4];
    f4 o[2] = {};
#pragma unroll
    for (int r = 0; r < 4; ++r) { m[r] = -3.0e38f; sum[r] = 0.0f; }

    for (int kb = 0; kb < NPTS / 64; ++kb) {
        int kr0 = kb * 64;
        f4 s4[4];
#pragma unroll
        for (int kt = 0; kt < 4; ++kt) {
            size_t koff = (size_t)(h * NPTS + kr0 + kt * 16 + lr) * HD + lg * 8;
            s8 kh = ld8(kHi + koff);
            s8 kl = ld8(kLo + koff);
            f4 a = {};
            a = MFMA(ql, kh, a);
            a = MFMA(qh, kl, a);
            a = MFMA(qh, kh, a);
            s4[kt] = a;
        }
        // scale + clip
#pragma unroll
        for (int kt = 0; kt < 4; ++kt)
#pragma unroll
            for (int r = 0; r < 4; ++r) {
                float s = s4[kt][r] * SCALE;
                s4[kt][r] = fminf(fmaxf(s, -100.0f), 100.0f);
            }
        // row max (within-lane over 4 k-subtiles, then across 16 lanes)
        float tm[4];
#pragma unroll
        for (int r = 0; r < 4; ++r)
            tm[r] = fmaxf(fmaxf(s4[0][r], s4[1][r]), fmaxf(s4[2][r], s4[3][r]));
#pragma unroll
        for (int mask = 1; mask < 16; mask <<= 1)
#pragma unroll
            for (int r = 0; r < 4; ++r) tm[r] = fmaxf(tm[r], __shfl_xor(tm[r], mask));
        float fac[4];
#pragma unroll
        for (int r = 0; r < 4; ++r) {
            float mn = fmaxf(m[r], tm[r]);
            fac[r] = expf(m[r] - mn);
            m[r] = mn;
            sum[r] *= fac[r];
        }
#pragma unroll
        for (int ct = 0; ct < 2; ++ct)
#pragma unroll
            for (int r = 0; r < 4; ++r) o[ct][r] *= fac[r];
        // exp + row sum
        float ps[4] = {0.0f, 0.0f, 0.0f, 0.0f};
#pragma unroll
        for (int kt = 0; kt < 4; ++kt)
#pragma unroll
            for (int r = 0; r < 4; ++r) {
                float p = expf(s4[kt][r] - m[r]);
                s4[kt][r] = p;
                ps[r] += p;
            }
#pragma unroll
        for (int mask = 1; mask < 16; mask <<= 1)
#pragma unroll
            for (int r = 0; r < 4; ++r) ps[r] += __shfl_xor(ps[r], mask);
#pragma unroll
        for (int r = 0; r < 4; ++r) sum[r] += ps[r];

        // P -> LDS (bf16), D-layout write, A-layout read
        __syncthreads();
#pragma unroll
        for (int kt = 0; kt < 4; ++kt)
#pragma unroll
            for (int r = 0; r < 4; ++r)
                pl[(lg * 4 + r) * 72 + kt * 16 + lr] = f2bf(s4[kt][r]);
        __syncthreads();

        s8 pa0 = ld8(&pl[lr * 72 + 0 + lg * 8]);
        s8 pa1 = ld8(&pl[lr * 72 + 32 + lg * 8]);
#pragma unroll
        for (int ct = 0; ct < 2; ++ct) {
            const u16* vb = vtHi + (size_t)(h * HD + ct * 16 + lr) * NPTS + kr0;
            const u16* vbl = vtLo + (size_t)(h * HD + ct * 16 + lr) * NPTS + kr0;
            s8 v0h = ld8(vb + lg * 8);
            s8 v0l = ld8(vbl + lg * 8);
            s8 v1h = ld8(vb + 32 + lg * 8);
            s8 v1l = ld8(vbl + 32 + lg * 8);
            o[ct] = MFMA(pa0, v0h, o[ct]);
            o[ct] = MFMA(pa0, v0l, o[ct]);
            o[ct] = MFMA(pa1, v1h, o[ct]);
            o[ct] = MFMA(pa1, v1l, o[ct]);
        }
    }
    // epilogue: divide by (sum + 1e-6), write cat layout [n][h*32+d]
#pragma unroll
    for (int ct = 0; ct < 2; ++ct)
#pragma unroll
        for (int r = 0; r < 4; ++r) {
            float val = o[ct][r] / (sum[r] + 1e-6f);
            int n = qb * 16 + lg * 4 + r;
            int c = h * HD + ct * 16 + lr;
            catH[n * 256 + c] = f2bf(val);
        }
}

// ---------------------------------------------------------------------------
// Phase 4: out = cat @ wo + bo + x   (bf16 MFMA, fp32 epilogue)
// Block 256 thr = 4 waves; wave 16 rows x 64 cols; grid (64, 4).
// ---------------------------------------------------------------------------
__global__ __launch_bounds__(256) void k_out(
        const u16* __restrict__ catH, const u16* __restrict__ woT,
        const float* __restrict__ bo, const float* __restrict__ x,
        float* __restrict__ out) {
    int w = threadIdx.x >> 6, l = threadIdx.x & 63;
    int lr = l & 15, lg = l >> 4;
    int r0 = blockIdx.x * 64 + w * 16;
    int c0 = blockIdx.y * 64;
    f4 acc[4] = {};
#pragma unroll
    for (int kk = 0; kk < 8; ++kk) {
        s8 a = ld8(catH + (r0 + lr) * 256 + kk * 32 + lg * 8);
#pragma unroll
        for (int ct = 0; ct < 4; ++ct) {
            s8 b = ld8(woT + (c0 + ct * 16 + lr) * 256 + kk * 32 + lg * 8);
            acc[ct] = MFMA(a, b, acc[ct]);
        }
    }
#pragma unroll
    for (int ct = 0; ct < 4; ++ct) {
        int c = c0 + ct * 16 + lr;
        float bias = bo[c];
#pragma unroll
        for (int r = 0; r < 4; ++r) {
            int n = r0 + lg * 4 + r;
            out[n * 256 + c] = acc[ct][r] + bias + x[n * 256 + c];
        }
    }
}

// ---------------------------------------------------------------------------
extern "C" void kernel_launch(void* const* d_in, const int* in_sizes, int n_in,
                              void* d_out, int out_size, void* d_ws, size_t ws_size,
                              hipStream_t stream) {
    const float* x      = (const float*)d_in[0];
    const int*   coords = (const int*)d_in[1];
    const float* wq     = (const float*)d_in[2];
    const float* bq     = (const float*)d_in[3];
    const float* wk     = (const float*)d_in[4];
    const float* bk     = (const float*)d_in[5];
    const float* wv     = (const float*)d_in[6];
    const float* bv     = (const float*)d_in[7];
    const float* wo     = (const float*)d_in[8];
    const float* bo     = (const float*)d_in[9];
    float* out = (float*)d_out;

    char* ws = (char*)d_ws;
    size_t off = 0;
    auto alloc = [&](size_t bytes) {
        char* p = ws + off;
        off = (off + bytes + 255) & ~(size_t)255;
        return p;
    };
    u16* xcHi = (u16*)alloc((size_t)NPTS * DINP * 2);
    u16* xcLo = (u16*)alloc((size_t)NPTS * DINP * 2);
    u16* wtHi = (u16*)alloc((size_t)COUT * DINP * 2);
    u16* wtLo = (u16*)alloc((size_t)COUT * DINP * 2);
    u16* qHi  = (u16*)alloc((size_t)NH * NPTS * HD * 2);
    u16* qLo  = (u16*)alloc((size_t)NH * NPTS * HD * 2);
    u16* kHi  = (u16*)alloc((size_t)NH * NPTS * HD * 2);
    u16* kLo  = (u16*)alloc((size_t)NH * NPTS * HD * 2);
    u16* vtHi = (u16*)alloc((size_t)NH * HD * NPTS * 2);
    u16* vtLo = (u16*)alloc((size_t)NH * HD * NPTS * 2);
    u16* catH = (u16*)alloc((size_t)NPTS * 256 * 2);
    u16* woT  = (u16*)alloc((size_t)256 * 256 * 2);
    (void)ws_size; (void)in_sizes; (void)n_in; (void)out_size;

    k_wprep<<<COUT, 64, 0, stream>>>(wq, wk, wv, wtHi, wtLo);
    k_woprep<<<256, 256, 0, stream>>>(wo, woT);
    k_featurize<<<NPTS, 64, 0, stream>>>(x, coords, xcHi, xcLo);
    k_qkv<<<dim3(NPTS / 64, COUT / 64), 256, 0, stream>>>(
        xcHi, xcLo, wtHi, wtLo, bq, bk, bv, qHi, qLo, kHi, kLo, vtHi, vtLo);
    k_attn<<<dim3(NPTS / 16, NH), 64, 0, stream>>>(qHi, qLo, kHi, kLo, vtHi, vtLo, catH);
    k_out<<<dim3(NPTS / 64, 256 / 64), 256, 0, stream>>>(catH, woT, bo, x, out);
}

// Round 2
// 233.553 us; speedup vs baseline: 1.2211x; 1.2211x over previous
//
#include <hip/hip_runtime.h>
#include <hip/hip_bf16.h>

// ---------------------------------------------------------------------------
// MultiHeadAttention: feats L2-norm + clamp(coords) concat -> per-head QKV
// (DIN=259, HD=32, H=8) -> softmax attention (N=4096, clip +-100, /(sum+1e-6))
// -> output proj + bias + residual.
// Precision: hi/lo bf16 split (3-MFMA fp32 emulation) for QKV proj and QK^T;
// bf16 P and bf16 V for PV; plain bf16 for output proj.
// Softmax runs in log2 domain with hardware v_exp_f32.
// ---------------------------------------------------------------------------

using s8 = __attribute__((ext_vector_type(8))) short;   // 8 x bf16 (4 VGPR)
using f4 = __attribute__((ext_vector_type(4))) float;   // MFMA C/D
typedef unsigned short u16;
typedef unsigned int   u32;

#define NPTS 4096
#define NH   8
#define HD   32
#define DIN  259
#define DINP 288       // padded K-dim for QKV GEMM (9 x 32)
#define COUT 768       // 3*NH*HD, col c = s*256 + h*32 + hd (s: 0=q,1=k,2=v)
#define KBLK 128       // attention keys per iteration
#define PLSTR 144      // LDS row stride (u16) for P tile: 8-bank octants per lg

#define MFMA(a, b, c) __builtin_amdgcn_mfma_f32_16x16x32_bf16((a), (b), (c), 0, 0, 0)

#if __has_builtin(__builtin_amdgcn_exp2f)
#define EXP2(x) __builtin_amdgcn_exp2f(x)
#else
#define EXP2(x) exp2f(x)
#endif

__device__ __forceinline__ u16 f2bf(float f) {
    u32 u = __float_as_uint(f);
    u32 r = u + 0x7FFFu + ((u >> 16) & 1u);   // round-to-nearest-even
    return (u16)(r >> 16);
}
__device__ __forceinline__ float bf2f(u16 h) { return __uint_as_float(((u32)h) << 16); }
__device__ __forceinline__ void splitbf(float v, u16& hi, u16& lo) {
    hi = f2bf(v);
    lo = f2bf(v - bf2f(hi));
}
__device__ __forceinline__ s8 ld8(const u16* p) { return *reinterpret_cast<const s8*>(p); }

// ---------------------------------------------------------------------------
// Phase 0a: build transposed+split QKV weight matrix Wt[COUT][DINP]
// ---------------------------------------------------------------------------
__global__ void k_wprep(const float* __restrict__ wq, const float* __restrict__ wk,
                        const float* __restrict__ wv,
                        u16* __restrict__ wtHi, u16* __restrict__ wtLo) {
    int c = blockIdx.x;                   // 0..767
    int s = c >> 8, h = (c >> 5) & 7, hd = c & 31;
    const float* w = (s == 0) ? wq : (s == 1) ? wk : wv;
    for (int k = threadIdx.x; k < DINP; k += blockDim.x) {
        float val = (k < DIN) ? w[(h * DIN + k) * HD + hd] : 0.0f;
        u16 hi, lo; splitbf(val, hi, lo);
        wtHi[c * DINP + k] = hi;
        wtLo[c * DINP + k] = lo;
    }
}

// ---------------------------------------------------------------------------
// Phase 0b: woT[c][k] = wo[k][c] (bf16)
// ---------------------------------------------------------------------------
__global__ void k_woprep(const float* __restrict__ wo, u16* __restrict__ woT) {
    int c = blockIdx.x;
    int k = threadIdx.x;                  // blockDim = 256
    woT[c * 256 + k] = f2bf(wo[k * 256 + c]);
}

// ---------------------------------------------------------------------------
// Phase 1: featurize. One 64-lane wave per row.
// ---------------------------------------------------------------------------
__global__ __launch_bounds__(64) void k_featurize(const float* __restrict__ x,
                                                  const int* __restrict__ coords,
                                                  u16* __restrict__ xcHi,
                                                  u16* __restrict__ xcLo) {
    int row = blockIdx.x;
    int l = threadIdx.x;
    f4 v = *reinterpret_cast<const f4*>(x + row * 256 + 4 * l);
    float ss = v[0] * v[0] + v[1] * v[1] + v[2] * v[2] + v[3] * v[3];
#pragma unroll
    for (int m = 1; m < 64; m <<= 1) ss += __shfl_xor(ss, m);
    float inv = 1.0f / (sqrtf(ss) + 1e-6f);
#pragma unroll
    for (int j = 0; j < 4; ++j) {
        u16 hi, lo; splitbf(v[j] * inv, hi, lo);
        xcHi[row * DINP + 4 * l + j] = hi;
        xcLo[row * DINP + 4 * l + j] = lo;
    }
    if (l < 32) {
        int col = 256 + l;
        float val = 0.0f;
        if (col < DIN) {
            float c = (float)coords[row * 3 + (col - 256)];
            val = fminf(fmaxf(c, -100.0f), 100.0f);
        }
        u16 hi, lo; splitbf(val, hi, lo);
        xcHi[row * DINP + col] = hi;
        xcLo[row * DINP + col] = lo;
    }
}

// ---------------------------------------------------------------------------
// Phase 2: QKV GEMM  [4096 x DINP] x [DINP x 768] with 3-MFMA emulation.
// q,k row-major [h][n][hd] (hi/lo); v transposed [h][hd][n] (hi only).
// ---------------------------------------------------------------------------
__global__ __launch_bounds__(256) void k_qkv(
        const u16* __restrict__ xcHi, const u16* __restrict__ xcLo,
        const u16* __restrict__ wtHi, const u16* __restrict__ wtLo,
        const float* __restrict__ bq, const float* __restrict__ bk,
        const float* __restrict__ bv,
        u16* __restrict__ qHi, u16* __restrict__ qLo,
        u16* __restrict__ kHi, u16* __restrict__ kLo,
        u16* __restrict__ vtHi) {
    int w = threadIdx.x >> 6, l = threadIdx.x & 63;
    int lr = l & 15, lg = l >> 4;
    int r0 = blockIdx.x * 64 + w * 16;    // wave's row base
    int c0 = blockIdx.y * 64;             // block's col base

    f4 acc[4] = {};
    const u16* aH = xcHi + (r0 + lr) * DINP + lg * 8;
    const u16* aL = xcLo + (r0 + lr) * DINP + lg * 8;
#pragma unroll
    for (int kk = 0; kk < 9; ++kk) {
        s8 ah = ld8(aH + kk * 32);
        s8 al = ld8(aL + kk * 32);
#pragma unroll
        for (int ct = 0; ct < 4; ++ct) {
            int c = c0 + ct * 16 + lr;
            s8 bh = ld8(wtHi + c * DINP + kk * 32 + lg * 8);
            s8 bl = ld8(wtLo + c * DINP + kk * 32 + lg * 8);
            acc[ct] = MFMA(al, bh, acc[ct]);
            acc[ct] = MFMA(ah, bl, acc[ct]);
            acc[ct] = MFMA(ah, bh, acc[ct]);
        }
    }
#pragma unroll
    for (int ct = 0; ct < 4; ++ct) {
        int c = c0 + ct * 16 + lr;
        int s = c >> 8, h = (c >> 5) & 7, hd = c & 31;
        float bias = ((s == 0) ? bq : (s == 1) ? bk : bv)[h * HD + hd];
#pragma unroll
        for (int r = 0; r < 4; ++r) {
            int n = r0 + lg * 4 + r;
            float val = acc[ct][r] + bias;
            if (s == 0) {
                u16 hi, lo; splitbf(val, hi, lo);
                qHi[(h * NPTS + n) * HD + hd] = hi;
                qLo[(h * NPTS + n) * HD + hd] = lo;
            } else if (s == 1) {
                u16 hi, lo; splitbf(val, hi, lo);
                kHi[(h * NPTS + n) * HD + hd] = hi;
                kLo[(h * NPTS + n) * HD + hd] = lo;
            } else {
                vtHi[(h * HD + hd) * NPTS + n] = f2bf(val);
            }
        }
    }
}

// ---------------------------------------------------------------------------
// Phase 3: attention. One 64-lane wave per (head, 16 q-rows). Online softmax
// in log2 domain. KBLK=128 keys per iteration.
// S tile = Q[16x32] . K^T (3-MFMA emulation); clip; v_exp; P bf16 via LDS;
// O += P.V (bf16 V).
// ---------------------------------------------------------------------------
__global__ __launch_bounds__(64) void k_attn(
        const u16* __restrict__ qHi, const u16* __restrict__ qLo,
        const u16* __restrict__ kHi, const u16* __restrict__ kLo,
        const u16* __restrict__ vtHi,
        u16* __restrict__ catH) {
    __shared__ u16 pl[16 * PLSTR];        // P tile [16 q][128 k]
    int qb = blockIdx.x;                  // 0..255
    int h = blockIdx.y;                   // 0..7
    int l = threadIdx.x, lr = l & 15, lg = l >> 4;
    // scale * log2(e): softmax in base-2 domain (monotone, identical p)
    const float SCL2 = 0.17677669529663687f * 1.4426950408889634f;
    const float CLIP2 = 100.0f * 1.4426950408889634f;

    size_t qoff = (size_t)(h * NPTS + qb * 16 + lr) * HD + lg * 8;
    s8 qh = ld8(qHi + qoff);
    s8 ql = ld8(qLo + qoff);

    float m[4], sum[4];
    f4 o[2] = {};
#pragma unroll
    for (int r = 0; r < 4; ++r) { m[r] = -1.0e30f; sum[r] = 0.0f; }

    for (int kb = 0; kb < NPTS / KBLK; ++kb) {
        int kr0 = kb * KBLK;
        f4 s4[8];
#pragma unroll
        for (int kt = 0; kt < 8; ++kt) {
            size_t koff = (size_t)(h * NPTS + kr0 + kt * 16 + lr) * HD + lg * 8;
            s8 kh = ld8(kHi + koff);
            s8 kl = ld8(kLo + koff);
            f4 a = {};
            a = MFMA(ql, kh, a);
            a = MFMA(qh, kl, a);
            a = MFMA(qh, kh, a);
            s4[kt] = a;
        }
        // scale into log2 domain + clip
#pragma unroll
        for (int kt = 0; kt < 8; ++kt)
#pragma unroll
            for (int r = 0; r < 4; ++r) {
                float s = s4[kt][r] * SCL2;
                s4[kt][r] = fminf(fmaxf(s, -CLIP2), CLIP2);
            }
        // row max: in-lane over 8 kt, then across the 16-lane key group
        float tm[4];
#pragma unroll
        for (int r = 0; r < 4; ++r) {
            float t0 = fmaxf(fmaxf(s4[0][r], s4[1][r]), fmaxf(s4[2][r], s4[3][r]));
            float t1 = fmaxf(fmaxf(s4[4][r], s4[5][r]), fmaxf(s4[6][r], s4[7][r]));
            tm[r] = fmaxf(t0, t1);
        }
#pragma unroll
        for (int mask = 1; mask < 16; mask <<= 1)
#pragma unroll
            for (int r = 0; r < 4; ++r) tm[r] = fmaxf(tm[r], __shfl_xor(tm[r], mask));
        float fac[4];
#pragma unroll
        for (int r = 0; r < 4; ++r) {
            float mn = fmaxf(m[r], tm[r]);
            fac[r] = EXP2(m[r] - mn);
            m[r] = mn;
            sum[r] *= fac[r];
        }
#pragma unroll
        for (int ct = 0; ct < 2; ++ct)
#pragma unroll
            for (int r = 0; r < 4; ++r) o[ct][r] *= fac[r];
        // p = 2^(s - m); accumulate row sums
        float ps[4] = {0.0f, 0.0f, 0.0f, 0.0f};
#pragma unroll
        for (int kt = 0; kt < 8; ++kt)
#pragma unroll
            for (int r = 0; r < 4; ++r) {
                float p = EXP2(s4[kt][r] - m[r]);
                s4[kt][r] = p;
                ps[r] += p;
            }
#pragma unroll
        for (int mask = 1; mask < 16; mask <<= 1)
#pragma unroll
            for (int r = 0; r < 4; ++r) ps[r] += __shfl_xor(ps[r], mask);
#pragma unroll
        for (int r = 0; r < 4; ++r) sum[r] += ps[r];

        // P -> LDS (bf16), D-layout write, A-layout read
        __syncthreads();
#pragma unroll
        for (int kt = 0; kt < 8; ++kt)
#pragma unroll
            for (int r = 0; r < 4; ++r)
                pl[(lg * 4 + r) * PLSTR + kt * 16 + lr] = f2bf(s4[kt][r]);
        __syncthreads();

        s8 pa[4];
#pragma unroll
        for (int c = 0; c < 4; ++c)
            pa[c] = ld8(&pl[lr * PLSTR + c * 32 + lg * 8]);
#pragma unroll
        for (int ct = 0; ct < 2; ++ct) {
            const u16* vb = vtHi + (size_t)(h * HD + ct * 16 + lr) * NPTS + kr0;
#pragma unroll
            for (int c = 0; c < 4; ++c) {
                s8 vv = ld8(vb + c * 32 + lg * 8);
                o[ct] = MFMA(pa[c], vv, o[ct]);
            }
        }
    }
    // epilogue: divide by (sum + 1e-6), write cat layout [n][h*32+d]
#pragma unroll
    for (int ct = 0; ct < 2; ++ct)
#pragma unroll
        for (int r = 0; r < 4; ++r) {
            float val = o[ct][r] / (sum[r] + 1e-6f);
            int n = qb * 16 + lg * 4 + r;
            int c = h * HD + ct * 16 + lr;
            catH[n * 256 + c] = f2bf(val);
        }
}

// ---------------------------------------------------------------------------
// Phase 4: out = cat @ wo + bo + x   (bf16 MFMA, fp32 epilogue)
// ---------------------------------------------------------------------------
__global__ __launch_bounds__(256) void k_out(
        const u16* __restrict__ catH, const u16* __restrict__ woT,
        const float* __restrict__ bo, const float* __restrict__ x,
        float* __restrict__ out) {
    int w = threadIdx.x >> 6, l = threadIdx.x & 63;
    int lr = l & 15, lg = l >> 4;
    int r0 = blockIdx.x * 64 + w * 16;
    int c0 = blockIdx.y * 64;
    f4 acc[4] = {};
#pragma unroll
    for (int kk = 0; kk < 8; ++kk) {
        s8 a = ld8(catH + (r0 + lr) * 256 + kk * 32 + lg * 8);
#pragma unroll
        for (int ct = 0; ct < 4; ++ct) {
            s8 b = ld8(woT + (c0 + ct * 16 + lr) * 256 + kk * 32 + lg * 8);
            acc[ct] = MFMA(a, b, acc[ct]);
        }
    }
#pragma unroll
    for (int ct = 0; ct < 4; ++ct) {
        int c = c0 + ct * 16 + lr;
        float bias = bo[c];
#pragma unroll
        for (int r = 0; r < 4; ++r) {
            int n = r0 + lg * 4 + r;
            out[n * 256 + c] = acc[ct][r] + bias + x[n * 256 + c];
        }
    }
}

// ---------------------------------------------------------------------------
extern "C" void kernel_launch(void* const* d_in, const int* in_sizes, int n_in,
                              void* d_out, int out_size, void* d_ws, size_t ws_size,
                              hipStream_t stream) {
    const float* x      = (const float*)d_in[0];
    const int*   coords = (const int*)d_in[1];
    const float* wq     = (const float*)d_in[2];
    const float* bq     = (const float*)d_in[3];
    const float* wk     = (const float*)d_in[4];
    const float* bk     = (const float*)d_in[5];
    const float* wv     = (const float*)d_in[6];
    const float* bv     = (const float*)d_in[7];
    const float* wo     = (const float*)d_in[8];
    const float* bo     = (const float*)d_in[9];
    float* out = (float*)d_out;

    char* ws = (char*)d_ws;
    size_t off = 0;
    auto alloc = [&](size_t bytes) {
        char* p = ws + off;
        off = (off + bytes + 255) & ~(size_t)255;
        return p;
    };
    u16* xcHi = (u16*)alloc((size_t)NPTS * DINP * 2);
    u16* xcLo = (u16*)alloc((size_t)NPTS * DINP * 2);
    u16* wtHi = (u16*)alloc((size_t)COUT * DINP * 2);
    u16* wtLo = (u16*)alloc((size_t)COUT * DINP * 2);
    u16* qHi  = (u16*)alloc((size_t)NH * NPTS * HD * 2);
    u16* qLo  = (u16*)alloc((size_t)NH * NPTS * HD * 2);
    u16* kHi  = (u16*)alloc((size_t)NH * NPTS * HD * 2);
    u16* kLo  = (u16*)alloc((size_t)NH * NPTS * HD * 2);
    u16* vtHi = (u16*)alloc((size_t)NH * HD * NPTS * 2);
    u16* catH = (u16*)alloc((size_t)NPTS * 256 * 2);
    u16* woT  = (u16*)alloc((size_t)256 * 256 * 2);
    (void)ws_size; (void)in_sizes; (void)n_in; (void)out_size;

    k_wprep<<<COUT, 64, 0, stream>>>(wq, wk, wv, wtHi, wtLo);
    k_woprep<<<256, 256, 0, stream>>>(wo, woT);
    k_featurize<<<NPTS, 64, 0, stream>>>(x, coords, xcHi, xcLo);
    k_qkv<<<dim3(NPTS / 64, COUT / 64), 256, 0, stream>>>(
        xcHi, xcLo, wtHi, wtLo, bq, bk, bv, qHi, qLo, kHi, kLo, vtHi);
    k_attn<<<dim3(NPTS / 16, NH), 64, 0, stream>>>(qHi, qLo, kHi, kLo, vtHi, catH);
    k_out<<<dim3(NPTS / 64, 256 / 64), 256, 0, stream>>>(catH, woT, bo, x, out);
}

// Round 3
// 208.969 us; speedup vs baseline: 1.3648x; 1.1176x over previous
//
#include <hip/hip_runtime.h>
#include <hip/hip_bf16.h>

// ---------------------------------------------------------------------------
// MultiHeadAttention: feats L2-norm + clamp(coords) concat -> per-head QKV
// (DIN=259, HD=32, H=8) -> softmax attention (N=4096, clip +-100, /(sum+1e-6))
// -> output proj + bias + residual.
// Precision: hi/lo bf16 split (3-MFMA fp32 emulation) for QKV proj and QK^T;
// bf16 P and bf16 V for PV; plain bf16 for output proj.
// Attention: swapped-operand QK^T (S^T = K.Q^T) so softmax is lane-local;
// PV via mfma 16x16x16 whose B-layout matches S^T D-layout (no LDS at all).
// ---------------------------------------------------------------------------

using s8  = __attribute__((ext_vector_type(8))) short;   // 8 x bf16 (4 VGPR)
using s4v = __attribute__((ext_vector_type(4))) short;   // 4 x bf16 (2 VGPR)
using f4  = __attribute__((ext_vector_type(4))) float;   // MFMA C/D
typedef unsigned short u16;
typedef unsigned int   u32;

#define NPTS 4096
#define NH   8
#define HD   32
#define DIN  259
#define DINP 288       // padded K-dim for QKV GEMM (9 x 32)
#define COUT 768       // 3*NH*HD, col c = s*256 + h*32 + hd (s: 0=q,1=k,2=v)
#define KBLK 128       // attention keys per iteration

#define MFMA32(a, b, c) __builtin_amdgcn_mfma_f32_16x16x32_bf16((a), (b), (c), 0, 0, 0)

#if __has_builtin(__builtin_amdgcn_mfma_f32_16x16x16bf16_1k)
#define HAVE_MFMA16 1
#define MFMA16(a, b, c) __builtin_amdgcn_mfma_f32_16x16x16bf16_1k((a), (b), (c), 0, 0, 0)
#else
#define HAVE_MFMA16 0
#endif

#if __has_builtin(__builtin_amdgcn_exp2f)
#define EXP2(x) __builtin_amdgcn_exp2f(x)
#else
#define EXP2(x) exp2f(x)
#endif

__device__ __forceinline__ u16 f2bf(float f) {
    u32 u = __float_as_uint(f);
    u32 r = u + 0x7FFFu + ((u >> 16) & 1u);   // round-to-nearest-even
    return (u16)(r >> 16);
}
__device__ __forceinline__ float bf2f(u16 h) { return __uint_as_float(((u32)h) << 16); }
__device__ __forceinline__ void splitbf(float v, u16& hi, u16& lo) {
    hi = f2bf(v);
    lo = f2bf(v - bf2f(hi));
}
__device__ __forceinline__ s8 ld8(const u16* p) { return *reinterpret_cast<const s8*>(p); }
__device__ __forceinline__ u32 bfpair(float a, float b) {
    return (u32)f2bf(a) | ((u32)f2bf(b) << 16);
}

// ---------------------------------------------------------------------------
// Phase 0a: build transposed+split QKV weight matrix Wt[COUT][DINP]
// ---------------------------------------------------------------------------
__global__ void k_wprep(const float* __restrict__ wq, const float* __restrict__ wk,
                        const float* __restrict__ wv,
                        u16* __restrict__ wtHi, u16* __restrict__ wtLo) {
    int c = blockIdx.x;                   // 0..767
    int s = c >> 8, h = (c >> 5) & 7, hd = c & 31;
    const float* w = (s == 0) ? wq : (s == 1) ? wk : wv;
    for (int k = threadIdx.x; k < DINP; k += blockDim.x) {
        float val = (k < DIN) ? w[(h * DIN + k) * HD + hd] : 0.0f;
        u16 hi, lo; splitbf(val, hi, lo);
        wtHi[c * DINP + k] = hi;
        wtLo[c * DINP + k] = lo;
    }
}

// ---------------------------------------------------------------------------
// Phase 0b: woT[c][k] = wo[k][c] (bf16)
// ---------------------------------------------------------------------------
__global__ void k_woprep(const float* __restrict__ wo, u16* __restrict__ woT) {
    int c = blockIdx.x;
    int k = threadIdx.x;                  // blockDim = 256
    woT[c * 256 + k] = f2bf(wo[k * 256 + c]);
}

// ---------------------------------------------------------------------------
// Phase 1: featurize. One 64-lane wave per row.
// ---------------------------------------------------------------------------
__global__ __launch_bounds__(64) void k_featurize(const float* __restrict__ x,
                                                  const int* __restrict__ coords,
                                                  u16* __restrict__ xcHi,
                                                  u16* __restrict__ xcLo) {
    int row = blockIdx.x;
    int l = threadIdx.x;
    f4 v = *reinterpret_cast<const f4*>(x + row * 256 + 4 * l);
    float ss = v[0] * v[0] + v[1] * v[1] + v[2] * v[2] + v[3] * v[3];
#pragma unroll
    for (int m = 1; m < 64; m <<= 1) ss += __shfl_xor(ss, m);
    float inv = 1.0f / (sqrtf(ss) + 1e-6f);
#pragma unroll
    for (int j = 0; j < 4; ++j) {
        u16 hi, lo; splitbf(v[j] * inv, hi, lo);
        xcHi[row * DINP + 4 * l + j] = hi;
        xcLo[row * DINP + 4 * l + j] = lo;
    }
    if (l < 32) {
        int col = 256 + l;
        float val = 0.0f;
        if (col < DIN) {
            float c = (float)coords[row * 3 + (col - 256)];
            val = fminf(fmaxf(c, -100.0f), 100.0f);
        }
        u16 hi, lo; splitbf(val, hi, lo);
        xcHi[row * DINP + col] = hi;
        xcLo[row * DINP + col] = lo;
    }
}

// ---------------------------------------------------------------------------
// Phase 2: QKV GEMM  [4096 x DINP] x [DINP x 768] with 3-MFMA emulation.
// q,k row-major [h][n][hd] (hi/lo); v tiled [h][n>>4][hd][n&15] (bf16).
// ---------------------------------------------------------------------------
__global__ __launch_bounds__(256) void k_qkv(
        const u16* __restrict__ xcHi, const u16* __restrict__ xcLo,
        const u16* __restrict__ wtHi, const u16* __restrict__ wtLo,
        const float* __restrict__ bq, const float* __restrict__ bk,
        const float* __restrict__ bv,
        u16* __restrict__ qHi, u16* __restrict__ qLo,
        u16* __restrict__ kHi, u16* __restrict__ kLo,
        u16* __restrict__ vt2) {
    int w = threadIdx.x >> 6, l = threadIdx.x & 63;
    int lr = l & 15, lg = l >> 4;
    int r0 = blockIdx.x * 64 + w * 16;    // wave's row base
    int c0 = blockIdx.y * 64;             // block's col base

    f4 acc[4] = {};
    const u16* aH = xcHi + (r0 + lr) * DINP + lg * 8;
    const u16* aL = xcLo + (r0 + lr) * DINP + lg * 8;
#pragma unroll
    for (int kk = 0; kk < 9; ++kk) {
        s8 ah = ld8(aH + kk * 32);
        s8 al = ld8(aL + kk * 32);
#pragma unroll
        for (int ct = 0; ct < 4; ++ct) {
            int c = c0 + ct * 16 + lr;
            s8 bh = ld8(wtHi + c * DINP + kk * 32 + lg * 8);
            s8 bl = ld8(wtLo + c * DINP + kk * 32 + lg * 8);
            acc[ct] = MFMA32(al, bh, acc[ct]);
            acc[ct] = MFMA32(ah, bl, acc[ct]);
            acc[ct] = MFMA32(ah, bh, acc[ct]);
        }
    }
#pragma unroll
    for (int ct = 0; ct < 4; ++ct) {
        int c = c0 + ct * 16 + lr;
        int s = c >> 8, h = (c >> 5) & 7, hd = c & 31;
        float bias = ((s == 0) ? bq : (s == 1) ? bk : bv)[h * HD + hd];
#pragma unroll
        for (int r = 0; r < 4; ++r) {
            int n = r0 + lg * 4 + r;
            float val = acc[ct][r] + bias;
            if (s == 0) {
                u16 hi, lo; splitbf(val, hi, lo);
                qHi[(h * NPTS + n) * HD + hd] = hi;
                qLo[(h * NPTS + n) * HD + hd] = lo;
            } else if (s == 1) {
                u16 hi, lo; splitbf(val, hi, lo);
                kHi[(h * NPTS + n) * HD + hd] = hi;
                kLo[(h * NPTS + n) * HD + hd] = lo;
            } else {
                // tiled V^T: [h][key tile][hd][key%16]
                vt2[((size_t)(h * 256 + (n >> 4)) * 32 + hd) * 16 + (n & 15)] = f2bf(val);
            }
        }
    }
}

// ---------------------------------------------------------------------------
// Phase 3: attention. One 64-lane wave per (head, 16 q-rows). No LDS, no
// barriers. S^T = K.Q^T via 3-MFMA emulation; lane-local softmax in log2
// domain; PV via 16x16x16 MFMA (B-frag == S^T D-frag layout).
// Grid 2048 1-D; blockIdx&7 = head -> per-XCD L2 holds one head's K/V.
// ---------------------------------------------------------------------------
__global__ __launch_bounds__(64) void k_attn(
        const u16* __restrict__ qHi, const u16* __restrict__ qLo,
        const u16* __restrict__ kHi, const u16* __restrict__ kLo,
        const u16* __restrict__ vt2,
        u16* __restrict__ catH) {
    int b = blockIdx.x;
    int h = b & 7;                        // head -> XCD affinity
    int qb = b >> 3;                      // 0..255
    int l = threadIdx.x, lr = l & 15, lg = l >> 4;
    const float SCL2 = 0.17677669529663687f * 1.4426950408889634f;
    const float CLIP2 = 100.0f * 1.4426950408889634f;

    size_t qoff = (size_t)(h * NPTS + qb * 16 + lr) * HD + lg * 8;
    s8 qh = ld8(qHi + qoff);
    s8 ql = ld8(qLo + qoff);

    float m = -1.0e30f, sum = 0.0f;
    f4 o0 = {}, o1 = {};

#pragma unroll 2
    for (int kb = 0; kb < NPTS / KBLK; ++kb) {
        int kr0 = kb * KBLK;
        // S^T tiles: st[kt] holds S^T[key = kt*16 + lg*4 + r][q = lr]
        f4 st[8];
#pragma unroll
        for (int kt = 0; kt < 8; ++kt) {
            size_t koff = (size_t)(h * NPTS + kr0 + kt * 16 + lr) * HD + lg * 8;
            s8 kh = ld8(kHi + koff);
            s8 kl = ld8(kLo + koff);
            f4 a = {};
            a = MFMA32(kl, qh, a);
            a = MFMA32(kh, ql, a);
            a = MFMA32(kh, qh, a);
            st[kt] = a;
        }
        // scale into log2 domain + clip
#pragma unroll
        for (int kt = 0; kt < 8; ++kt)
#pragma unroll
            for (int r = 0; r < 4; ++r) {
                float s = st[kt][r] * SCL2;
                st[kt][r] = fminf(fmaxf(s, -CLIP2), CLIP2);
            }
        // row max: in-lane tree over 32 keys + butterfly across 4 lane groups
        float tm = -1.0e30f;
#pragma unroll
        for (int kt = 0; kt < 8; ++kt) {
            float t = fmaxf(fmaxf(st[kt][0], st[kt][1]), fmaxf(st[kt][2], st[kt][3]));
            tm = fmaxf(tm, t);
        }
        tm = fmaxf(tm, __shfl_xor(tm, 16));
        tm = fmaxf(tm, __shfl_xor(tm, 32));
        float mn = fmaxf(m, tm);
        float fac = EXP2(m - mn);
        m = mn;
        sum *= fac;
#pragma unroll
        for (int r = 0; r < 4; ++r) { o0[r] *= fac; o1[r] *= fac; }
        // p = 2^(s-m), partial sums (4 parallel chains)
        float ps0 = 0.0f, ps1 = 0.0f, ps2 = 0.0f, ps3 = 0.0f;
#pragma unroll
        for (int kt = 0; kt < 8; ++kt) {
            float p0 = EXP2(st[kt][0] - m); st[kt][0] = p0; ps0 += p0;
            float p1 = EXP2(st[kt][1] - m); st[kt][1] = p1; ps1 += p1;
            float p2 = EXP2(st[kt][2] - m); st[kt][2] = p2; ps2 += p2;
            float p3 = EXP2(st[kt][3] - m); st[kt][3] = p3; ps3 += p3;
        }
        float ps = (ps0 + ps1) + (ps2 + ps3);
        ps += __shfl_xor(ps, 16);
        ps += __shfl_xor(ps, 32);
        sum += ps;

        // PV: O^T += V^T . P^T
        const u16* vbase = vt2 + (size_t)(h * 256 + kb * 8) * 512;
#if HAVE_MFMA16
#pragma unroll
        for (int kt = 0; kt < 8; ++kt) {
            s4v pb;
            pb[0] = (short)f2bf(st[kt][0]);
            pb[1] = (short)f2bf(st[kt][1]);
            pb[2] = (short)f2bf(st[kt][2]);
            pb[3] = (short)f2bf(st[kt][3]);
            const u16* vt = vbase + kt * 512;
            s4v v0 = *reinterpret_cast<const s4v*>(vt + lr * 16 + lg * 4);
            s4v v1 = *reinterpret_cast<const s4v*>(vt + (16 + lr) * 16 + lg * 4);
            o0 = MFMA16(v0, pb, o0);
            o1 = MFMA16(v1, pb, o1);
        }
#else
        // fallback: assemble 16x16x32 B-frags via shuffles
        u32 pk0[8], pk1[8];
#pragma unroll
        for (int kt = 0; kt < 8; ++kt) {
            pk0[kt] = bfpair(st[kt][0], st[kt][1]);
            pk1[kt] = bfpair(st[kt][2], st[kt][3]);
        }
        int srcbase = ((lg & 1) * 2) * 16 + lr;
        bool hiQuad = (lg >> 1) != 0;
#pragma unroll
        for (int s = 0; s < 4; ++s) {
            union { u32 u[4]; s8 v; } bu;
#pragma unroll
            for (int wi = 0; wi < 4; ++wi) {
                int src = srcbase + ((wi >> 1) << 4);
                u32 a0 = (u32)__shfl((int)((wi & 1) ? pk1[2 * s] : pk0[2 * s]), src);
                u32 a1 = (u32)__shfl((int)((wi & 1) ? pk1[2 * s + 1] : pk0[2 * s + 1]), src);
                bu.u[wi] = hiQuad ? a1 : a0;
            }
            int t = 2 * s + (lg >> 1);
            const u16* vt = vbase + t * 512 + (lg & 1) * 8;
            s8 v0 = ld8(vt + lr * 16);
            s8 v1 = ld8(vt + (16 + lr) * 16);
            o0 = MFMA32(v0, bu.v, o0);
            o1 = MFMA32(v1, bu.v, o1);
        }
#endif
    }
    // epilogue: o holds O^T[hd = ct*16 + lg*4 + r][q = lr]
    float inv = 1.0f / (sum + 1e-6f);
    int n = qb * 16 + lr;
    u16* dst0 = catH + n * 256 + h * HD + lg * 4;
    u32 w0 = bfpair(o0[0] * inv, o0[1] * inv);
    u32 w1 = bfpair(o0[2] * inv, o0[3] * inv);
    *reinterpret_cast<uint2*>(dst0) = make_uint2(w0, w1);
    u16* dst1 = dst0 + 16;
    u32 w2 = bfpair(o1[0] * inv, o1[1] * inv);
    u32 w3 = bfpair(o1[2] * inv, o1[3] * inv);
    *reinterpret_cast<uint2*>(dst1) = make_uint2(w2, w3);
}

// ---------------------------------------------------------------------------
// Phase 4: out = cat @ wo + bo + x   (bf16 MFMA, fp32 epilogue)
// ---------------------------------------------------------------------------
__global__ __launch_bounds__(256) void k_out(
        const u16* __restrict__ catH, const u16* __restrict__ woT,
        const float* __restrict__ bo, const float* __restrict__ x,
        float* __restrict__ out) {
    int w = threadIdx.x >> 6, l = threadIdx.x & 63;
    int lr = l & 15, lg = l >> 4;
    int r0 = blockIdx.x * 64 + w * 16;
    int c0 = blockIdx.y * 64;
    f4 acc[4] = {};
#pragma unroll
    for (int kk = 0; kk < 8; ++kk) {
        s8 a = ld8(catH + (r0 + lr) * 256 + kk * 32 + lg * 8);
#pragma unroll
        for (int ct = 0; ct < 4; ++ct) {
            s8 b = ld8(woT + (c0 + ct * 16 + lr) * 256 + kk * 32 + lg * 8);
            acc[ct] = MFMA32(a, b, acc[ct]);
        }
    }
#pragma unroll
    for (int ct = 0; ct < 4; ++ct) {
        int c = c0 + ct * 16 + lr;
        float bias = bo[c];
#pragma unroll
        for (int r = 0; r < 4; ++r) {
            int n = r0 + lg * 4 + r;
            out[n * 256 + c] = acc[ct][r] + bias + x[n * 256 + c];
        }
    }
}

// ---------------------------------------------------------------------------
extern "C" void kernel_launch(void* const* d_in, const int* in_sizes, int n_in,
                              void* d_out, int out_size, void* d_ws, size_t ws_size,
                              hipStream_t stream) {
    const float* x      = (const float*)d_in[0];
    const int*   coords = (const int*)d_in[1];
    const float* wq     = (const float*)d_in[2];
    const float* bq     = (const float*)d_in[3];
    const float* wk     = (const float*)d_in[4];
    const float* bk     = (const float*)d_in[5];
    const float* wv     = (const float*)d_in[6];
    const float* bv     = (const float*)d_in[7];
    const float* wo     = (const float*)d_in[8];
    const float* bo     = (const float*)d_in[9];
    float* out = (float*)d_out;

    char* ws = (char*)d_ws;
    size_t off = 0;
    auto alloc = [&](size_t bytes) {
        char* p = ws + off;
        off = (off + bytes + 255) & ~(size_t)255;
        return p;
    };
    u16* xcHi = (u16*)alloc((size_t)NPTS * DINP * 2);
    u16* xcLo = (u16*)alloc((size_t)NPTS * DINP * 2);
    u16* wtHi = (u16*)alloc((size_t)COUT * DINP * 2);
    u16* wtLo = (u16*)alloc((size_t)COUT * DINP * 2);
    u16* qHi  = (u16*)alloc((size_t)NH * NPTS * HD * 2);
    u16* qLo  = (u16*)alloc((size_t)NH * NPTS * HD * 2);
    u16* kHi  = (u16*)alloc((size_t)NH * NPTS * HD * 2);
    u16* kLo  = (u16*)alloc((size_t)NH * NPTS * HD * 2);
    u16* vt2  = (u16*)alloc((size_t)NH * NPTS * HD * 2);
    u16* catH = (u16*)alloc((size_t)NPTS * 256 * 2);
    u16* woT  = (u16*)alloc((size_t)256 * 256 * 2);
    (void)ws_size; (void)in_sizes; (void)n_in; (void)out_size;

    k_wprep<<<COUT, 64, 0, stream>>>(wq, wk, wv, wtHi, wtLo);
    k_woprep<<<256, 256, 0, stream>>>(wo, woT);
    k_featurize<<<NPTS, 64, 0, stream>>>(x, coords, xcHi, xcLo);
    k_qkv<<<dim3(NPTS / 64, COUT / 64), 256, 0, stream>>>(
        xcHi, xcLo, wtHi, wtLo, bq, bk, bv, qHi, qLo, kHi, kLo, vt2);
    k_attn<<<NPTS / 16 * NH, 64, 0, stream>>>(qHi, qLo, kHi, kLo, vt2, catH);
    k_out<<<dim3(NPTS / 64, 256 / 64), 256, 0, stream>>>(catH, woT, bo, x, out);
}

// Round 4
// 148.273 us; speedup vs baseline: 1.9235x; 1.4094x over previous
//
#include <hip/hip_runtime.h>
#include <hip/hip_bf16.h>

// ---------------------------------------------------------------------------
// MultiHeadAttention: feats L2-norm + clamp(coords) concat -> per-head QKV
// (DIN=259, HD=32, H=8) -> softmax attention (N=4096, clip +-100, /(sum+1e-6))
// -> output proj + bias + residual.
// Precision: hi/lo bf16 split (3-MFMA fp32 emulation) for QKV proj and QK^T;
// bf16 P and bf16 V for PV; plain bf16 for output proj.
// Attention: swapped-operand QK^T (S^T = K.Q^T) so softmax is lane-local;
// PV via mfma 16x16x16 (B-frag == S^T D-frag layout); split-K across 4 waves
// per block (flash-decoding) + LDS merge for occupancy.
// ---------------------------------------------------------------------------

using s8  = __attribute__((ext_vector_type(8))) short;   // 8 x bf16 (4 VGPR)
using s4v = __attribute__((ext_vector_type(4))) short;   // 4 x bf16 (2 VGPR)
using f4  = __attribute__((ext_vector_type(4))) float;   // MFMA C/D
typedef unsigned short u16;
typedef unsigned int   u32;

#define NPTS 4096
#define NH   8
#define HD   32
#define DIN  259
#define DINP 288       // padded K-dim for QKV GEMM (9 x 32)
#define COUT 768       // 3*NH*HD, col c = s*256 + h*32 + hd (s: 0=q,1=k,2=v)
#define KBLK 128       // attention keys per inner iteration
#define KSPLIT 4       // waves per block, each takes NPTS/KSPLIT keys

#define MFMA32(a, b, c) __builtin_amdgcn_mfma_f32_16x16x32_bf16((a), (b), (c), 0, 0, 0)

#if __has_builtin(__builtin_amdgcn_mfma_f32_16x16x16bf16_1k)
#define HAVE_MFMA16 1
#define MFMA16(a, b, c) __builtin_amdgcn_mfma_f32_16x16x16bf16_1k((a), (b), (c), 0, 0, 0)
#else
#define HAVE_MFMA16 0
#endif

#if __has_builtin(__builtin_amdgcn_exp2f)
#define EXP2(x) __builtin_amdgcn_exp2f(x)
#else
#define EXP2(x) exp2f(x)
#endif

__device__ __forceinline__ u16 f2bf(float f) {
    u32 u = __float_as_uint(f);
    u32 r = u + 0x7FFFu + ((u >> 16) & 1u);   // round-to-nearest-even
    return (u16)(r >> 16);
}
__device__ __forceinline__ float bf2f(u16 h) { return __uint_as_float(((u32)h) << 16); }
__device__ __forceinline__ void splitbf(float v, u16& hi, u16& lo) {
    hi = f2bf(v);
    lo = f2bf(v - bf2f(hi));
}
__device__ __forceinline__ s8 ld8(const u16* p) { return *reinterpret_cast<const s8*>(p); }
__device__ __forceinline__ u32 bfpair(float a, float b) {
    return (u32)f2bf(a) | ((u32)f2bf(b) << 16);
}

// ---------------------------------------------------------------------------
// Phase 0a: build transposed+split QKV weight matrix Wt[COUT][DINP]
// ---------------------------------------------------------------------------
__global__ void k_wprep(const float* __restrict__ wq, const float* __restrict__ wk,
                        const float* __restrict__ wv,
                        u16* __restrict__ wtHi, u16* __restrict__ wtLo) {
    int c = blockIdx.x;                   // 0..767
    int s = c >> 8, h = (c >> 5) & 7, hd = c & 31;
    const float* w = (s == 0) ? wq : (s == 1) ? wk : wv;
    for (int k = threadIdx.x; k < DINP; k += blockDim.x) {
        float val = (k < DIN) ? w[(h * DIN + k) * HD + hd] : 0.0f;
        u16 hi, lo; splitbf(val, hi, lo);
        wtHi[c * DINP + k] = hi;
        wtLo[c * DINP + k] = lo;
    }
}

// ---------------------------------------------------------------------------
// Phase 0b: woT[c][k] = wo[k][c] (bf16)
// ---------------------------------------------------------------------------
__global__ void k_woprep(const float* __restrict__ wo, u16* __restrict__ woT) {
    int c = blockIdx.x;
    int k = threadIdx.x;                  // blockDim = 256
    woT[c * 256 + k] = f2bf(wo[k * 256 + c]);
}

// ---------------------------------------------------------------------------
// Phase 1: featurize. One 64-lane wave per row.
// ---------------------------------------------------------------------------
__global__ __launch_bounds__(64) void k_featurize(const float* __restrict__ x,
                                                  const int* __restrict__ coords,
                                                  u16* __restrict__ xcHi,
                                                  u16* __restrict__ xcLo) {
    int row = blockIdx.x;
    int l = threadIdx.x;
    f4 v = *reinterpret_cast<const f4*>(x + row * 256 + 4 * l);
    float ss = v[0] * v[0] + v[1] * v[1] + v[2] * v[2] + v[3] * v[3];
#pragma unroll
    for (int m = 1; m < 64; m <<= 1) ss += __shfl_xor(ss, m);
    float inv = 1.0f / (sqrtf(ss) + 1e-6f);
#pragma unroll
    for (int j = 0; j < 4; ++j) {
        u16 hi, lo; splitbf(v[j] * inv, hi, lo);
        xcHi[row * DINP + 4 * l + j] = hi;
        xcLo[row * DINP + 4 * l + j] = lo;
    }
    if (l < 32) {
        int col = 256 + l;
        float val = 0.0f;
        if (col < DIN) {
            float c = (float)coords[row * 3 + (col - 256)];
            val = fminf(fmaxf(c, -100.0f), 100.0f);
        }
        u16 hi, lo; splitbf(val, hi, lo);
        xcHi[row * DINP + col] = hi;
        xcLo[row * DINP + col] = lo;
    }
}

// ---------------------------------------------------------------------------
// Phase 2: QKV GEMM  [4096 x DINP] x [DINP x 768] with 3-MFMA emulation.
// q,k row-major [h][n][hd] (hi/lo); v tiled [h][n>>4][hd][n&15] (bf16).
// ---------------------------------------------------------------------------
__global__ __launch_bounds__(256) void k_qkv(
        const u16* __restrict__ xcHi, const u16* __restrict__ xcLo,
        const u16* __restrict__ wtHi, const u16* __restrict__ wtLo,
        const float* __restrict__ bq, const float* __restrict__ bk,
        const float* __restrict__ bv,
        u16* __restrict__ qHi, u16* __restrict__ qLo,
        u16* __restrict__ kHi, u16* __restrict__ kLo,
        u16* __restrict__ vt2) {
    int w = threadIdx.x >> 6, l = threadIdx.x & 63;
    int lr = l & 15, lg = l >> 4;
    int r0 = blockIdx.x * 64 + w * 16;    // wave's row base
    int c0 = blockIdx.y * 64;             // block's col base

    f4 acc[4] = {};
    const u16* aH = xcHi + (r0 + lr) * DINP + lg * 8;
    const u16* aL = xcLo + (r0 + lr) * DINP + lg * 8;
#pragma unroll
    for (int kk = 0; kk < 9; ++kk) {
        s8 ah = ld8(aH + kk * 32);
        s8 al = ld8(aL + kk * 32);
#pragma unroll
        for (int ct = 0; ct < 4; ++ct) {
            int c = c0 + ct * 16 + lr;
            s8 bh = ld8(wtHi + c * DINP + kk * 32 + lg * 8);
            s8 bl = ld8(wtLo + c * DINP + kk * 32 + lg * 8);
            acc[ct] = MFMA32(al, bh, acc[ct]);
            acc[ct] = MFMA32(ah, bl, acc[ct]);
            acc[ct] = MFMA32(ah, bh, acc[ct]);
        }
    }
#pragma unroll
    for (int ct = 0; ct < 4; ++ct) {
        int c = c0 + ct * 16 + lr;
        int s = c >> 8, h = (c >> 5) & 7, hd = c & 31;
        float bias = ((s == 0) ? bq : (s == 1) ? bk : bv)[h * HD + hd];
#pragma unroll
        for (int r = 0; r < 4; ++r) {
            int n = r0 + lg * 4 + r;
            float val = acc[ct][r] + bias;
            if (s == 0) {
                u16 hi, lo; splitbf(val, hi, lo);
                qHi[(h * NPTS + n) * HD + hd] = hi;
                qLo[(h * NPTS + n) * HD + hd] = lo;
            } else if (s == 1) {
                u16 hi, lo; splitbf(val, hi, lo);
                kHi[(h * NPTS + n) * HD + hd] = hi;
                kLo[(h * NPTS + n) * HD + hd] = lo;
            } else {
                // tiled V^T: [h][key tile][hd][key%16]
                vt2[((size_t)(h * 256 + (n >> 4)) * 32 + hd) * 16 + (n & 15)] = f2bf(val);
            }
        }
    }
}

// ---------------------------------------------------------------------------
// Phase 3: attention, split-K flash-decoding. Block = 4 waves on one
// (head, 16 q-rows); wave w handles keys [w*1024, w*1024+1024). Swapped
// QK^T (S^T = K.Q^T, 3-MFMA emulation), lane-local log2 softmax, PV via
// 16x16x16 MFMA. LDS merge of {m, sum, O} at the end; wave 0 writes.
// blockIdx&7 = head -> per-XCD L2 holds one head's K/V.
// ---------------------------------------------------------------------------
__global__ __launch_bounds__(256) void k_attn(
        const u16* __restrict__ qHi, const u16* __restrict__ qLo,
        const u16* __restrict__ kHi, const u16* __restrict__ kLo,
        const u16* __restrict__ vt2,
        u16* __restrict__ catH) {
    __shared__ float cmb[KSPLIT][64][13];  // {m,sum,o0[4],o1[4]} stride 13: no bank conflict
    int b = blockIdx.x;
    int h = b & 7;                        // head -> XCD affinity
    int qb = b >> 3;                      // 0..255
    int w = threadIdx.x >> 6;             // key-split index
    int l = threadIdx.x & 63, lr = l & 15, lg = l >> 4;
    const float SCL2 = 0.17677669529663687f * 1.4426950408889634f;
    const float CLIP2 = 100.0f * 1.4426950408889634f;

    size_t qoff = (size_t)(h * NPTS + qb * 16 + lr) * HD + lg * 8;
    s8 qh = ld8(qHi + qoff);
    s8 ql = ld8(qLo + qoff);

    float m = -1.0e30f, sum = 0.0f;
    f4 o0 = {}, o1 = {};

#pragma unroll 2
    for (int kb = w * (NPTS / KSPLIT / KBLK); kb < (w + 1) * (NPTS / KSPLIT / KBLK); ++kb) {
        int kr0 = kb * KBLK;
        // S^T tiles: st[kt] holds S^T[key = kt*16 + lg*4 + r][q = lr]
        f4 st[8];
#pragma unroll
        for (int kt = 0; kt < 8; ++kt) {
            size_t koff = (size_t)(h * NPTS + kr0 + kt * 16 + lr) * HD + lg * 8;
            s8 kh = ld8(kHi + koff);
            s8 kl = ld8(kLo + koff);
            f4 a = {};
            a = MFMA32(kl, qh, a);
            a = MFMA32(kh, ql, a);
            a = MFMA32(kh, qh, a);
            st[kt] = a;
        }
        // scale into log2 domain + clip
#pragma unroll
        for (int kt = 0; kt < 8; ++kt)
#pragma unroll
            for (int r = 0; r < 4; ++r) {
                float s = st[kt][r] * SCL2;
                st[kt][r] = fminf(fmaxf(s, -CLIP2), CLIP2);
            }
        // row max: in-lane tree over 32 keys + butterfly across 4 lane groups
        float tm = -1.0e30f;
#pragma unroll
        for (int kt = 0; kt < 8; ++kt) {
            float t = fmaxf(fmaxf(st[kt][0], st[kt][1]), fmaxf(st[kt][2], st[kt][3]));
            tm = fmaxf(tm, t);
        }
        tm = fmaxf(tm, __shfl_xor(tm, 16));
        tm = fmaxf(tm, __shfl_xor(tm, 32));
        float mn = fmaxf(m, tm);
        float fac = EXP2(m - mn);
        m = mn;
        sum *= fac;
#pragma unroll
        for (int r = 0; r < 4; ++r) { o0[r] *= fac; o1[r] *= fac; }
        // p = 2^(s-m), partial sums (4 parallel chains)
        float ps0 = 0.0f, ps1 = 0.0f, ps2 = 0.0f, ps3 = 0.0f;
#pragma unroll
        for (int kt = 0; kt < 8; ++kt) {
            float p0 = EXP2(st[kt][0] - m); st[kt][0] = p0; ps0 += p0;
            float p1 = EXP2(st[kt][1] - m); st[kt][1] = p1; ps1 += p1;
            float p2 = EXP2(st[kt][2] - m); st[kt][2] = p2; ps2 += p2;
            float p3 = EXP2(st[kt][3] - m); st[kt][3] = p3; ps3 += p3;
        }
        float ps = (ps0 + ps1) + (ps2 + ps3);
        ps += __shfl_xor(ps, 16);
        ps += __shfl_xor(ps, 32);
        sum += ps;

        // PV: O^T += V^T . P^T
        const u16* vbase = vt2 + (size_t)(h * 256 + kb * 8) * 512;
#if HAVE_MFMA16
#pragma unroll
        for (int kt = 0; kt < 8; ++kt) {
            s4v pb;
            pb[0] = (short)f2bf(st[kt][0]);
            pb[1] = (short)f2bf(st[kt][1]);
            pb[2] = (short)f2bf(st[kt][2]);
            pb[3] = (short)f2bf(st[kt][3]);
            const u16* vt = vbase + kt * 512;
            s4v v0 = *reinterpret_cast<const s4v*>(vt + lr * 16 + lg * 4);
            s4v v1 = *reinterpret_cast<const s4v*>(vt + (16 + lr) * 16 + lg * 4);
            o0 = MFMA16(v0, pb, o0);
            o1 = MFMA16(v1, pb, o1);
        }
#else
        // fallback: assemble 16x16x32 B-frags via shuffles
        u32 pk0[8], pk1[8];
#pragma unroll
        for (int kt = 0; kt < 8; ++kt) {
            pk0[kt] = bfpair(st[kt][0], st[kt][1]);
            pk1[kt] = bfpair(st[kt][2], st[kt][3]);
        }
        int srcbase = ((lg & 1) * 2) * 16 + lr;
        bool hiQuad = (lg >> 1) != 0;
#pragma unroll
        for (int s = 0; s < 4; ++s) {
            union { u32 u[4]; s8 v; } bu;
#pragma unroll
            for (int wi = 0; wi < 4; ++wi) {
                int src = srcbase + ((wi >> 1) << 4);
                u32 a0 = (u32)__shfl((int)((wi & 1) ? pk1[2 * s] : pk0[2 * s]), src);
                u32 a1 = (u32)__shfl((int)((wi & 1) ? pk1[2 * s + 1] : pk0[2 * s + 1]), src);
                bu.u[wi] = hiQuad ? a1 : a0;
            }
            int t = 2 * s + (lg >> 1);
            const u16* vt = vbase + t * 512 + (lg & 1) * 8;
            s8 v0 = ld8(vt + lr * 16);
            s8 v1 = ld8(vt + (16 + lr) * 16);
            o0 = MFMA32(v0, bu.v, o0);
            o1 = MFMA32(v1, bu.v, o1);
        }
#endif
    }

    // deposit per-wave partials
    float* c = cmb[w][l];
    c[0] = m; c[1] = sum;
#pragma unroll
    for (int r = 0; r < 4; ++r) { c[2 + r] = o0[r]; c[6 + r] = o1[r]; }
    __syncthreads();

    if (w == 0) {
        float M = cmb[0][l][0];
#pragma unroll
        for (int ww = 1; ww < KSPLIT; ++ww) M = fmaxf(M, cmb[ww][l][0]);
        float S = 0.0f;
        f4 O0 = {}, O1 = {};
#pragma unroll
        for (int ww = 0; ww < KSPLIT; ++ww) {
            const float* cc = cmb[ww][l];
            float fac = EXP2(cc[0] - M);
            S += fac * cc[1];
#pragma unroll
            for (int r = 0; r < 4; ++r) {
                O0[r] += fac * cc[2 + r];
                O1[r] += fac * cc[6 + r];
            }
        }
        float inv = 1.0f / (S + 1e-6f);
        int n = qb * 16 + lr;
        u16* dst0 = catH + n * 256 + h * HD + lg * 4;
        u32 w0 = bfpair(O0[0] * inv, O0[1] * inv);
        u32 w1 = bfpair(O0[2] * inv, O0[3] * inv);
        *reinterpret_cast<uint2*>(dst0) = make_uint2(w0, w1);
        u16* dst1 = dst0 + 16;
        u32 w2 = bfpair(O1[0] * inv, O1[1] * inv);
        u32 w3 = bfpair(O1[2] * inv, O1[3] * inv);
        *reinterpret_cast<uint2*>(dst1) = make_uint2(w2, w3);
    }
}

// ---------------------------------------------------------------------------
// Phase 4: out = cat @ wo + bo + x   (bf16 MFMA, fp32 epilogue)
// ---------------------------------------------------------------------------
__global__ __launch_bounds__(256) void k_out(
        const u16* __restrict__ catH, const u16* __restrict__ woT,
        const float* __restrict__ bo, const float* __restrict__ x,
        float* __restrict__ out) {
    int w = threadIdx.x >> 6, l = threadIdx.x & 63;
    int lr = l & 15, lg = l >> 4;
    int r0 = blockIdx.x * 64 + w * 16;
    int c0 = blockIdx.y * 64;
    f4 acc[4] = {};
#pragma unroll
    for (int kk = 0; kk < 8; ++kk) {
        s8 a = ld8(catH + (r0 + lr) * 256 + kk * 32 + lg * 8);
#pragma unroll
        for (int ct = 0; ct < 4; ++ct) {
            s8 b = ld8(woT + (c0 + ct * 16 + lr) * 256 + kk * 32 + lg * 8);
            acc[ct] = MFMA32(a, b, acc[ct]);
        }
    }
#pragma unroll
    for (int ct = 0; ct < 4; ++ct) {
        int c = c0 + ct * 16 + lr;
        float bias = bo[c];
#pragma unroll
        for (int r = 0; r < 4; ++r) {
            int n = r0 + lg * 4 + r;
            out[n * 256 + c] = acc[ct][r] + bias + x[n * 256 + c];
        }
    }
}

// ---------------------------------------------------------------------------
extern "C" void kernel_launch(void* const* d_in, const int* in_sizes, int n_in,
                              void* d_out, int out_size, void* d_ws, size_t ws_size,
                              hipStream_t stream) {
    const float* x      = (const float*)d_in[0];
    const int*   coords = (const int*)d_in[1];
    const float* wq     = (const float*)d_in[2];
    const float* bq     = (const float*)d_in[3];
    const float* wk     = (const float*)d_in[4];
    const float* bk     = (const float*)d_in[5];
    const float* wv     = (const float*)d_in[6];
    const float* bv     = (const float*)d_in[7];
    const float* wo     = (const float*)d_in[8];
    const float* bo     = (const float*)d_in[9];
    float* out = (float*)d_out;

    char* ws = (char*)d_ws;
    size_t off = 0;
    auto alloc = [&](size_t bytes) {
        char* p = ws + off;
        off = (off + bytes + 255) & ~(size_t)255;
        return p;
    };
    u16* xcHi = (u16*)alloc((size_t)NPTS * DINP * 2);
    u16* xcLo = (u16*)alloc((size_t)NPTS * DINP * 2);
    u16* wtHi = (u16*)alloc((size_t)COUT * DINP * 2);
    u16* wtLo = (u16*)alloc((size_t)COUT * DINP * 2);
    u16* qHi  = (u16*)alloc((size_t)NH * NPTS * HD * 2);
    u16* qLo  = (u16*)alloc((size_t)NH * NPTS * HD * 2);
    u16* kHi  = (u16*)alloc((size_t)NH * NPTS * HD * 2);
    u16* kLo  = (u16*)alloc((size_t)NH * NPTS * HD * 2);
    u16* vt2  = (u16*)alloc((size_t)NH * NPTS * HD * 2);
    u16* catH = (u16*)alloc((size_t)NPTS * 256 * 2);
    u16* woT  = (u16*)alloc((size_t)256 * 256 * 2);
    (void)ws_size; (void)in_sizes; (void)n_in; (void)out_size;

    k_wprep<<<COUT, 64, 0, stream>>>(wq, wk, wv, wtHi, wtLo);
    k_woprep<<<256, 256, 0, stream>>>(wo, woT);
    k_featurize<<<NPTS, 64, 0, stream>>>(x, coords, xcHi, xcLo);
    k_qkv<<<dim3(NPTS / 64, COUT / 64), 256, 0, stream>>>(
        xcHi, xcLo, wtHi, wtLo, bq, bk, bv, qHi, qLo, kHi, kLo, vt2);
    k_attn<<<NPTS / 16 * NH, 256, 0, stream>>>(qHi, qLo, kHi, kLo, vt2, catH);
    k_out<<<dim3(NPTS / 64, 256 / 64), 256, 0, stream>>>(catH, woT, bo, x, out);
}